// Round 3
// baseline (789.993 us; speedup 1.0000x reference)
//
#include <hip/hip_runtime.h>
#include <hip/hip_bf16.h>

#define DIM 2048
#define NH 16
#define KVH 4
#define HD 128
#define BATCH 2
#define SEQ 2048
#define MTOT (BATCH*SEQ)
#define SCALE 0.08838834764831845f

using f32x4 = __attribute__((ext_vector_type(4))) float;
using s16x4 = __attribute__((ext_vector_type(4))) short;
using s16x8 = __attribute__((ext_vector_type(8))) short;
using bf16x8 = __attribute__((ext_vector_type(8))) __bf16;

__device__ inline short f2bf(float x) { __bf16 h = (__bf16)x; return __builtin_bit_cast(short, h); }
__device__ inline float bf2f(short s) { return (float)__builtin_bit_cast(__bf16, s); }

// Load an 8-elem MFMA fragment: 4 elems at p, 4 at p+16 (uniform enumeration everywhere).
__device__ inline bf16x8 ld_frag(const short* p) {
  s16x4 lo = *(const s16x4*)p;
  s16x4 hi = *(const s16x4*)(p + 16);
  s16x8 f = __builtin_shufflevector(lo, hi, 0, 1, 2, 3, 4, 5, 6, 7);
  return __builtin_bit_cast(bf16x8, f);
}

// ---------------- prep kernels ----------------

__global__ void k_rope_table(float* __restrict__ tab) {
  int n = blockIdx.x, i = threadIdx.x;  // i in [0,64)
  float inv = expf(-(2.f * i / (float)HD) * logf(10000.f));
  float a = (float)n * inv;
  tab[n * HD + i] = cosf(a);
  tab[n * HD + 64 + i] = sinf(a);
}

__global__ void k_cvt_bf16(const float* __restrict__ in, short* __restrict__ out, int n4) {
  int i = blockIdx.x * 256 + threadIdx.x;
  if (i >= n4) return;
  f32x4 v = *(const f32x4*)(in + (size_t)i * 4);
  s16x4 o;
  o[0] = f2bf(v[0]); o[1] = f2bf(v[1]); o[2] = f2bf(v[2]); o[3] = f2bf(v[3]);
  *(s16x4*)(out + (size_t)i * 4) = o;
}

// W f32 [K][N] -> WT bf16 [N][K]
__global__ __launch_bounds__(256) void k_transpose(const float* __restrict__ W, short* __restrict__ WT,
                                                   int K, int N) {
  __shared__ float t[32][33];
  int n0 = blockIdx.x * 32, k0 = blockIdx.y * 32;
  int tx = threadIdx.x & 31, ty = threadIdx.x >> 5;
#pragma unroll
  for (int i = 0; i < 4; i++) t[ty + i * 8][tx] = W[(size_t)(k0 + ty + i * 8) * N + n0 + tx];
  __syncthreads();
#pragma unroll
  for (int i = 0; i < 4; i++) WT[(size_t)(n0 + ty + i * 8) * K + k0 + tx] = f2bf(t[tx][ty + i * 8]);
}

// ---------------- GEMM: C = A @ BT^T ----------------
// A [M][K] bf16 rm, BT [N][K] bf16 rm.
// MODE 0: C fp32 [M][N].  MODE 1: C bf16 permuted to [B][HH][SEQ][HD].
template <int MODE, int HH>
__device__ inline void gemm_bt_body(const short* __restrict__ A, const short* __restrict__ BT,
                                    void* __restrict__ C, int M, int N, int K) {
  __shared__ short As[128 * 32];
  __shared__ short Bs[128 * 32];
  const int tid = threadIdx.x;
  const int wid = tid >> 6, lane = tid & 63;
  const int m0 = blockIdx.y * 128, n0 = blockIdx.x * 128;
  const int wr = wid >> 1, wc = wid & 1;
  const int l15 = lane & 15, g4 = (lane >> 4) * 4;
  const int lrow = lane >> 2;         // 0..15
  const int lcol = (lane & 3) * 8;    // 0,8,16,24
  f32x4 acc[4][4] = {};

  for (int kt = 0; kt < K; kt += 32) {
    __syncthreads();
#pragma unroll
    for (int i = 0; i < 2; i++) {
      int r0 = wid * 32 + i * 16;
      const short* gp = A + (long)(m0 + r0 + lrow) * K + kt + lcol;
      __builtin_amdgcn_global_load_lds((const __attribute__((address_space(1))) void*)gp,
                                       (__attribute__((address_space(3))) void*)&As[r0 * 32], 16, 0, 0);
      const short* gq = BT + (long)(n0 + r0 + lrow) * K + kt + lcol;
      __builtin_amdgcn_global_load_lds((const __attribute__((address_space(1))) void*)gq,
                                       (__attribute__((address_space(3))) void*)&Bs[r0 * 32], 16, 0, 0);
    }
    __syncthreads();
    bf16x8 av[4];
#pragma unroll
    for (int mt = 0; mt < 4; mt++) av[mt] = ld_frag(&As[(wr * 64 + mt * 16 + l15) * 32 + g4]);
#pragma unroll
    for (int nt = 0; nt < 4; nt++) {
      bf16x8 bv = ld_frag(&Bs[(wc * 64 + nt * 16 + l15) * 32 + g4]);
#pragma unroll
      for (int mt = 0; mt < 4; mt++)
        acc[mt][nt] = __builtin_amdgcn_mfma_f32_16x16x32_bf16(av[mt], bv, acc[mt][nt], 0, 0, 0);
    }
  }

#pragma unroll
  for (int mt = 0; mt < 4; mt++) {
#pragma unroll
    for (int nt = 0; nt < 4; nt++) {
      int row = m0 + wr * 64 + mt * 16 + g4;
      int col = n0 + wc * 64 + nt * 16 + l15;
#pragma unroll
      for (int r = 0; r < 4; r++) {
        float v = acc[mt][nt][r];
        if (MODE == 0) {
          ((float*)C)[(long)(row + r) * N + col] = v;
        } else {
          int rg = row + r;
          int b = rg >> 11, n = rg & (SEQ - 1);
          int h = col >> 7, hd = col & (HD - 1);
          ((short*)C)[(((long)(b * HH + h)) * SEQ + n) * HD + hd] = f2bf(v);
        }
      }
    }
  }
}

__global__ __launch_bounds__(256) void k_gemm_q(const short* __restrict__ A, const short* __restrict__ BT,
                                                short* __restrict__ C, int M, int N, int K) {
  gemm_bt_body<1, NH>(A, BT, (void*)C, M, N, K);
}
__global__ __launch_bounds__(256) void k_gemm_kv(const short* __restrict__ A,
                                                 const short* __restrict__ BT0, const short* __restrict__ BT1,
                                                 short* __restrict__ C0, short* __restrict__ C1,
                                                 int M, int N, int K) {
  const short* BT = blockIdx.z ? BT1 : BT0;
  short* C = blockIdx.z ? C1 : C0;
  gemm_bt_body<1, KVH>(A, BT, (void*)C, M, N, K);
}
__global__ __launch_bounds__(256) void k_gemm_o(const short* __restrict__ A, const short* __restrict__ BT,
                                                float* __restrict__ C, int M, int N, int K) {
  gemm_bt_body<0, 0>(A, BT, (void*)C, M, N, K);
}

// ---------------- RoPE in-place on [.][heads][SEQ][HD] bf16 ----------------
__global__ void k_rope(short* __restrict__ t, const float* __restrict__ tab, int total) {
  int idx = blockIdx.x * 256 + threadIdx.x;
  if (idx >= total) return;
  int i = idx & 63;
  int n = (idx >> 6) & (SEQ - 1);
  long base = (long)(idx >> 6) * HD;
  float c = tab[n * HD + i], s = tab[n * HD + 64 + i];
  float x1 = bf2f(t[base + i]), x2 = bf2f(t[base + 64 + i]);
  t[base + i] = f2bf(x1 * c - x2 * s);
  t[base + 64 + i] = f2bf(x2 * c + x1 * s);
}

// ---------------- flash attention ----------------
// q_r [B][NH][SEQ][HD], k_r/v_r [B][KVH][SEQ][HD] bf16; out [B*SEQ][NH*HD] bf16
__global__ __launch_bounds__(256) void k_attn(const short* __restrict__ q_r, const short* __restrict__ k_r,
                                              const short* __restrict__ v_r, short* __restrict__ attn_out) {
  __shared__ short Kl[64 * 136];      // [kv 64][hd 128 pad 136]
  __shared__ short Vt[128 * 68];      // [hd 128][kv 64 pad 68] (transposed)
  __shared__ short Pl[4][16 * 68];    // per-wave P [16 q][64 kv pad 68]
  const int tid = threadIdx.x, wid = tid >> 6, lane = tid & 63;
  const int l15 = lane & 15, g4 = (lane >> 4) * 4;
  const int qt = blockIdx.x;
  const int bh = blockIdx.y;
  const int b = bh >> 4, h = bh & 15, kvh = h >> 2;
  const int q0 = qt * 64;

  const long qbase = (((long)(b * NH + h)) * SEQ + q0 + wid * 16) * HD;
  bf16x8 aq[4];
#pragma unroll
  for (int kt = 0; kt < 4; kt++) aq[kt] = ld_frag(q_r + qbase + (long)l15 * HD + kt * 32 + g4);

  f32x4 acc[8] = {};
  float m_[4] = {-1e30f, -1e30f, -1e30f, -1e30f};
  float l_[4] = {0.f, 0.f, 0.f, 0.f};
  const long kvbase = ((long)(b * KVH + kvh)) * SEQ * HD;
  const int nkt = qt + 1;

  for (int t64 = 0; t64 < nkt; t64++) {
    const int kv0 = t64 * 64;
    __syncthreads();  // previous-iteration LDS reads done
#pragma unroll
    for (int i = 0; i < 4; i++) {
      int c = tid + i * 256;
      int row = c >> 4, chk = c & 15;
      const long gsrc = kvbase + (long)(kv0 + row) * HD + chk * 8;
      s16x8 kv = *(const s16x8*)(k_r + gsrc);
      *(s16x8*)&Kl[row * 136 + chk * 8] = kv;
      s16x8 vv = *(const s16x8*)(v_r + gsrc);
#pragma unroll
      for (int e = 0; e < 8; e++) Vt[(chk * 8 + e) * 68 + row] = vv[e];
    }
    __syncthreads();

    // S = q @ K^T   (16x64 per wave)
    f32x4 s[4] = {};
#pragma unroll
    for (int nt = 0; nt < 4; nt++) {
#pragma unroll
      for (int kt = 0; kt < 4; kt++) {
        bf16x8 bk = ld_frag(&Kl[(nt * 16 + l15) * 136 + kt * 32 + g4]);
        s[nt] = __builtin_amdgcn_mfma_f32_16x16x32_bf16(aq[kt], bk, s[nt], 0, 0, 0);
      }
    }

    // scale + causal mask. D layout: row=(lane>>4)*4+r, col=lane&15 (m89-verified)
    const int rowg = q0 + wid * 16 + g4;
#pragma unroll
    for (int nt = 0; nt < 4; nt++) {
      int colg = kv0 + nt * 16 + l15;
#pragma unroll
      for (int r = 0; r < 4; r++) {
        float v = s[nt][r] * SCALE;
        s[nt][r] = (colg > rowg + r) ? -1e30f : v;
      }
    }

    // online softmax, per row r (16 cols live in the 16 lanes of the subgroup)
    float pex[4][4];
    float corr[4];
#pragma unroll
    for (int r = 0; r < 4; r++) {
      float tm = fmaxf(fmaxf(s[0][r], s[1][r]), fmaxf(s[2][r], s[3][r]));
#pragma unroll
      for (int mask = 1; mask < 16; mask <<= 1) tm = fmaxf(tm, __shfl_xor(tm, mask));
      float mn = fmaxf(m_[r], tm);
      corr[r] = __expf(m_[r] - mn);
      m_[r] = mn;
      float rs = 0.f;
#pragma unroll
      for (int nt = 0; nt < 4; nt++) {
        float p = __expf(s[nt][r] - mn);
        pex[nt][r] = p;
        rs += p;
      }
#pragma unroll
      for (int mask = 1; mask < 16; mask <<= 1) rs += __shfl_xor(rs, mask);
      l_[r] = l_[r] * corr[r] + rs;
    }
#pragma unroll
    for (int dt = 0; dt < 8; dt++)
#pragma unroll
      for (int r = 0; r < 4; r++) acc[dt][r] *= corr[r];

    // P -> bf16 -> per-wave LDS (same-wave dep, no barrier needed)
#pragma unroll
    for (int nt = 0; nt < 4; nt++)
#pragma unroll
      for (int r = 0; r < 4; r++) Pl[wid][(g4 + r) * 68 + nt * 16 + l15] = f2bf(pex[nt][r]);

    // O += P @ V
#pragma unroll
    for (int k2 = 0; k2 < 2; k2++) {
      bf16x8 ap = ld_frag(&Pl[wid][l15 * 68 + k2 * 32 + g4]);
#pragma unroll
      for (int dt = 0; dt < 8; dt++) {
        bf16x8 bv = ld_frag(&Vt[(dt * 16 + l15) * 68 + k2 * 32 + g4]);
        acc[dt] = __builtin_amdgcn_mfma_f32_16x16x32_bf16(ap, bv, acc[dt], 0, 0, 0);
      }
    }
  }

  const long obase = ((long)(b * SEQ + q0 + wid * 16 + g4)) * (NH * HD) + (long)h * HD;
#pragma unroll
  for (int r = 0; r < 4; r++) {
    float inv = 1.f / l_[r];
#pragma unroll
    for (int dt = 0; dt < 8; dt++)
      attn_out[obase + (long)r * (NH * HD) + dt * 16 + l15] = f2bf(acc[dt][r] * inv);
  }
}

// ---------------- launch ----------------
extern "C" void kernel_launch(void* const* d_in, const int* in_sizes, int n_in,
                              void* d_out, int out_size, void* d_ws, size_t ws_size,
                              hipStream_t stream) {
  const float* x = (const float*)d_in[0];
  const float* Wq = (const float*)d_in[1];
  const float* Wk = (const float*)d_in[2];
  const float* Wv = (const float*)d_in[3];
  const float* Wo = (const float*)d_in[4];

  char* w = (char*)d_ws;
  float* ropetab = (float*)w;  w += (size_t)SEQ * HD * 4;
  short* xb  = (short*)w;  w += (size_t)MTOT * DIM * 2;
  short* WqT = (short*)w;  w += (size_t)DIM * DIM * 2;
  short* WkT = (short*)w;  w += (size_t)(KVH * HD) * DIM * 2;
  short* WvT = (short*)w;  w += (size_t)(KVH * HD) * DIM * 2;
  short* WoT = (short*)w;  w += (size_t)DIM * DIM * 2;
  short* q_r = (short*)w;  w += (size_t)BATCH * NH * SEQ * HD * 2;
  short* k_r = (short*)w;  w += (size_t)BATCH * KVH * SEQ * HD * 2;
  short* v_r = (short*)w;  w += (size_t)BATCH * KVH * SEQ * HD * 2;
  short* attn = (short*)w; w += (size_t)MTOT * DIM * 2;

  k_rope_table<<<SEQ, 64, 0, stream>>>(ropetab);
  k_cvt_bf16<<<(MTOT * DIM / 4 + 255) / 256, 256, 0, stream>>>(x, xb, MTOT * DIM / 4);
  k_transpose<<<dim3(DIM / 32, DIM / 32), 256, 0, stream>>>(Wq, WqT, DIM, DIM);
  k_transpose<<<dim3((KVH * HD) / 32, DIM / 32), 256, 0, stream>>>(Wk, WkT, DIM, KVH * HD);
  k_transpose<<<dim3((KVH * HD) / 32, DIM / 32), 256, 0, stream>>>(Wv, WvT, DIM, KVH * HD);
  k_transpose<<<dim3(DIM / 32, DIM / 32), 256, 0, stream>>>(Wo, WoT, DIM, DIM);

  k_gemm_q<<<dim3(DIM / 128, MTOT / 128), 256, 0, stream>>>(xb, WqT, q_r, MTOT, DIM, DIM);
  k_gemm_kv<<<dim3((KVH * HD) / 128, MTOT / 128, 2), 256, 0, stream>>>(xb, WkT, WvT, k_r, v_r,
                                                                       MTOT, KVH * HD, DIM);
  k_rope<<<(BATCH * NH * SEQ * 64 + 255) / 256, 256, 0, stream>>>(q_r, ropetab, BATCH * NH * SEQ * 64);
  k_rope<<<(BATCH * KVH * SEQ * 64 + 255) / 256, 256, 0, stream>>>(k_r, ropetab, BATCH * KVH * SEQ * 64);

  k_attn<<<dim3(SEQ / 64, BATCH * NH), 256, 0, stream>>>(q_r, k_r, v_r, attn);
  k_gemm_o<<<dim3(DIM / 128, MTOT / 128), 256, 0, stream>>>(attn, WoT, (float*)d_out, MTOT, DIM, DIM);
}

// Round 4
// 692.389 us; speedup vs baseline: 1.1410x; 1.1410x over previous
//
#include <hip/hip_runtime.h>
#include <hip/hip_bf16.h>

#define DIM 2048
#define NH 16
#define KVH 4
#define HD 128
#define BATCH 2
#define SEQ 2048
#define MTOT (BATCH*SEQ)
#define SCALE 0.08838834764831845f

using f32x4 = __attribute__((ext_vector_type(4))) float;
using s16x4 = __attribute__((ext_vector_type(4))) short;
using s16x8 = __attribute__((ext_vector_type(8))) short;
using bf16x8 = __attribute__((ext_vector_type(8))) __bf16;

__device__ inline short f2bf(float x) { __bf16 h = (__bf16)x; return __builtin_bit_cast(short, h); }
__device__ inline float bf2f(short s) { return (float)__builtin_bit_cast(__bf16, s); }

// Load an 8-elem MFMA fragment: 4 elems at p, 4 at p+16 (uniform enumeration everywhere).
__device__ inline bf16x8 ld_frag(const short* p) {
  s16x4 lo = *(const s16x4*)p;
  s16x4 hi = *(const s16x4*)(p + 16);
  s16x8 f = __builtin_shufflevector(lo, hi, 0, 1, 2, 3, 4, 5, 6, 7);
  return __builtin_bit_cast(bf16x8, f);
}

// ---------------- prep kernels ----------------

__global__ void k_rope_table(float* __restrict__ tab) {
  int n = blockIdx.x, i = threadIdx.x;  // i in [0,64)
  float inv = expf(-(2.f * i / (float)HD) * logf(10000.f));
  float a = (float)n * inv;
  tab[n * HD + i] = cosf(a);
  tab[n * HD + 64 + i] = sinf(a);
}

__global__ void k_cvt_bf16(const float* __restrict__ in, short* __restrict__ out, int n4) {
  int i = blockIdx.x * 256 + threadIdx.x;
  if (i >= n4) return;
  f32x4 v = *(const f32x4*)(in + (size_t)i * 4);
  s16x4 o;
  o[0] = f2bf(v[0]); o[1] = f2bf(v[1]); o[2] = f2bf(v[2]); o[3] = f2bf(v[3]);
  *(s16x4*)(out + (size_t)i * 4) = o;
}

// W f32 [K][N] -> WT bf16 [N][K]
__global__ __launch_bounds__(256) void k_transpose(const float* __restrict__ W, short* __restrict__ WT,
                                                   int K, int N) {
  __shared__ float t[32][33];
  int n0 = blockIdx.x * 32, k0 = blockIdx.y * 32;
  int tx = threadIdx.x & 31, ty = threadIdx.x >> 5;
#pragma unroll
  for (int i = 0; i < 4; i++) t[ty + i * 8][tx] = W[(size_t)(k0 + ty + i * 8) * N + n0 + tx];
  __syncthreads();
#pragma unroll
  for (int i = 0; i < 4; i++) WT[(size_t)(n0 + ty + i * 8) * K + k0 + tx] = f2bf(t[tx][ty + i * 8]);
}

// V bf16 [.][SEQ][HD] -> [.][HD][SEQ], 64x64 tiles
__global__ __launch_bounds__(256) void k_transpose_v(const short* __restrict__ v_r, short* __restrict__ v_t) {
  __shared__ short t[64][70];
  const int z = blockIdx.z;
  const int s0 = blockIdx.x * 64, d0 = blockIdx.y * 64;
  const long ibase = ((long)z * SEQ + s0) * HD + d0;
  const long obase = ((long)z * HD + d0) * SEQ + s0;
  const int tid = threadIdx.x;
#pragma unroll
  for (int c = 0; c < 4; c++) {
    int chunk = tid + c * 256;              // 0..1023
    int row = chunk >> 4, col4 = (chunk & 15) * 4;
    *(s16x4*)&t[row][col4] = *(const s16x4*)(v_r + ibase + (long)row * HD + col4);
  }
  __syncthreads();
#pragma unroll
  for (int c = 0; c < 4; c++) {
    int chunk = tid + c * 256;
    int row = chunk >> 4, col4 = (chunk & 15) * 4; // row: hd idx, col4: seq chunk
    s16x4 o;
    o[0] = t[col4 + 0][row]; o[1] = t[col4 + 1][row];
    o[2] = t[col4 + 2][row]; o[3] = t[col4 + 3][row];
    *(s16x4*)(v_t + obase + (long)row * SEQ + col4) = o;
  }
}

// ---------------- GEMM: C = A @ BT^T ----------------
// A [M][K] bf16 rm, BT [N][K] bf16 rm.
// MODE 0: C fp32 [M][N].  MODE 1: C bf16 permuted to [B][HH][SEQ][HD].
template <int MODE, int HH>
__device__ inline void gemm_bt_body(const short* __restrict__ A, const short* __restrict__ BT,
                                    void* __restrict__ C, int M, int N, int K) {
  __shared__ short As[128 * 32];
  __shared__ short Bs[128 * 32];
  const int tid = threadIdx.x;
  const int wid = tid >> 6, lane = tid & 63;
  const int m0 = blockIdx.y * 128, n0 = blockIdx.x * 128;
  const int wr = wid >> 1, wc = wid & 1;
  const int l15 = lane & 15, g4 = (lane >> 4) * 4;
  const int lrow = lane >> 2;         // 0..15
  const int lcol = (lane & 3) * 8;    // 0,8,16,24
  f32x4 acc[4][4] = {};

  for (int kt = 0; kt < K; kt += 32) {
    __syncthreads();
#pragma unroll
    for (int i = 0; i < 2; i++) {
      int r0 = wid * 32 + i * 16;
      const short* gp = A + (long)(m0 + r0 + lrow) * K + kt + lcol;
      __builtin_amdgcn_global_load_lds((const __attribute__((address_space(1))) void*)gp,
                                       (__attribute__((address_space(3))) void*)&As[r0 * 32], 16, 0, 0);
      const short* gq = BT + (long)(n0 + r0 + lrow) * K + kt + lcol;
      __builtin_amdgcn_global_load_lds((const __attribute__((address_space(1))) void*)gq,
                                       (__attribute__((address_space(3))) void*)&Bs[r0 * 32], 16, 0, 0);
    }
    __syncthreads();
    bf16x8 av[4];
#pragma unroll
    for (int mt = 0; mt < 4; mt++) av[mt] = ld_frag(&As[(wr * 64 + mt * 16 + l15) * 32 + g4]);
#pragma unroll
    for (int nt = 0; nt < 4; nt++) {
      bf16x8 bv = ld_frag(&Bs[(wc * 64 + nt * 16 + l15) * 32 + g4]);
#pragma unroll
      for (int mt = 0; mt < 4; mt++)
        acc[mt][nt] = __builtin_amdgcn_mfma_f32_16x16x32_bf16(av[mt], bv, acc[mt][nt], 0, 0, 0);
    }
  }

#pragma unroll
  for (int mt = 0; mt < 4; mt++) {
#pragma unroll
    for (int nt = 0; nt < 4; nt++) {
      int row = m0 + wr * 64 + mt * 16 + g4;
      int col = n0 + wc * 64 + nt * 16 + l15;
#pragma unroll
      for (int r = 0; r < 4; r++) {
        float v = acc[mt][nt][r];
        if (MODE == 0) {
          ((float*)C)[(long)(row + r) * N + col] = v;
        } else {
          int rg = row + r;
          int b = rg >> 11, n = rg & (SEQ - 1);
          int h = col >> 7, hd = col & (HD - 1);
          ((short*)C)[(((long)(b * HH + h)) * SEQ + n) * HD + hd] = f2bf(v);
        }
      }
    }
  }
}

__global__ __launch_bounds__(256) void k_gemm_q(const short* __restrict__ A, const short* __restrict__ BT,
                                                short* __restrict__ C, int M, int N, int K) {
  gemm_bt_body<1, NH>(A, BT, (void*)C, M, N, K);
}
__global__ __launch_bounds__(256) void k_gemm_kv(const short* __restrict__ A,
                                                 const short* __restrict__ BT0, const short* __restrict__ BT1,
                                                 short* __restrict__ C0, short* __restrict__ C1,
                                                 int M, int N, int K) {
  const short* BT = blockIdx.z ? BT1 : BT0;
  short* C = blockIdx.z ? C1 : C0;
  gemm_bt_body<1, KVH>(A, BT, (void*)C, M, N, K);
}
__global__ __launch_bounds__(256) void k_gemm_o(const short* __restrict__ A, const short* __restrict__ BT,
                                                float* __restrict__ C, int M, int N, int K) {
  gemm_bt_body<0, 0>(A, BT, (void*)C, M, N, K);
}

// ---------------- RoPE in-place on [.][heads][SEQ][HD] bf16, optional scale fold ----------------
__global__ void k_rope(short* __restrict__ t, const float* __restrict__ tab, int total, float scale) {
  int idx = blockIdx.x * 256 + threadIdx.x;
  if (idx >= total) return;
  int i = idx & 63;
  int n = (idx >> 6) & (SEQ - 1);
  long base = (long)(idx >> 6) * HD;
  float c = tab[n * HD + i], s = tab[n * HD + 64 + i];
  float x1 = bf2f(t[base + i]), x2 = bf2f(t[base + 64 + i]);
  t[base + i] = f2bf((x1 * c - x2 * s) * scale);
  t[base + 64 + i] = f2bf((x2 * c + x1 * s) * scale);
}

// ---------------- flash attention ----------------
// q_r [B][NH][SEQ][HD] (pre-scaled), k_r [B][KVH][SEQ][HD], v_t [B][KVH][HD][SEQ] bf16
// out [B*SEQ][NH*HD] bf16
__global__ __launch_bounds__(256) void k_attn(const short* __restrict__ q_r, const short* __restrict__ k_r,
                                              const short* __restrict__ v_t, short* __restrict__ attn_out) {
  __shared__ short Kl[64 * 136];      // [kv 64][hd 128 pad 136]
  __shared__ short Vt[128 * 68];      // [hd 128][kv 64 pad 68]
  __shared__ short Pl[4][16 * 68];    // per-wave P [16 q][64 kv pad 68]
  const int tid = threadIdx.x, wid = tid >> 6, lane = tid & 63;
  const int l15 = lane & 15, g4 = (lane >> 4) * 4;
  const int qt = (int)(gridDim.x - 1) - blockIdx.x;  // heavy blocks first
  const int bh = blockIdx.y;
  const int b = bh >> 4, h = bh & 15, kvh = h >> 2;
  const int q0 = qt * 64;

  const long qbase = (((long)(b * NH + h)) * SEQ + q0 + wid * 16) * HD;
  bf16x8 aq[4];
#pragma unroll
  for (int kt = 0; kt < 4; kt++) aq[kt] = ld_frag(q_r + qbase + (long)l15 * HD + kt * 32 + g4);

  f32x4 acc[8] = {};
  float m_[4] = {-1e30f, -1e30f, -1e30f, -1e30f};
  float l_[4] = {0.f, 0.f, 0.f, 0.f};
  const long kvbase = ((long)(b * KVH + kvh)) * SEQ * HD;   // k_r head base
  const long vtbase = ((long)(b * KVH + kvh)) * HD * SEQ;   // v_t head base
  const int nkt = qt + 1;

  // T14 async-stage: tile t+1 global->reg issued under tile t compute
  s16x8 kreg[4], vreg[4];
#pragma unroll
  for (int c = 0; c < 4; c++) {
    int chunk = tid + c * 256;
    int kr = chunk >> 4, kc = (chunk & 15) * 8;
    kreg[c] = *(const s16x8*)(k_r + kvbase + (long)kr * HD + kc);
    int vr = chunk >> 3, vc = (chunk & 7) * 8;
    vreg[c] = *(const s16x8*)(v_t + vtbase + (long)vr * SEQ + vc);
  }

  for (int t64 = 0; t64 < nkt; t64++) {
    __syncthreads();  // previous-iteration LDS reads done
#pragma unroll
    for (int c = 0; c < 4; c++) {
      int chunk = tid + c * 256;
      int kr = chunk >> 4, kc = (chunk & 15) * 8;
      *(s16x8*)&Kl[kr * 136 + kc] = kreg[c];
      int vr = chunk >> 3, vc = (chunk & 7) * 8;
      *(s16x8*)&Vt[vr * 68 + vc] = vreg[c];
    }
    __syncthreads();

    if (t64 + 1 < nkt) {
      const int kv0n = (t64 + 1) * 64;
#pragma unroll
      for (int c = 0; c < 4; c++) {
        int chunk = tid + c * 256;
        int kr = chunk >> 4, kc = (chunk & 15) * 8;
        kreg[c] = *(const s16x8*)(k_r + kvbase + (long)(kv0n + kr) * HD + kc);
        int vr = chunk >> 3, vc = (chunk & 7) * 8;
        vreg[c] = *(const s16x8*)(v_t + vtbase + (long)vr * SEQ + kv0n + vc);
      }
    }

    const int kv0 = t64 * 64;
    // S = q @ K^T   (16x64 per wave), scale pre-folded into q
    f32x4 s[4] = {};
#pragma unroll
    for (int nt = 0; nt < 4; nt++) {
#pragma unroll
      for (int kt = 0; kt < 4; kt++) {
        bf16x8 bk = ld_frag(&Kl[(nt * 16 + l15) * 136 + kt * 32 + g4]);
        s[nt] = __builtin_amdgcn_mfma_f32_16x16x32_bf16(aq[kt], bk, s[nt], 0, 0, 0);
      }
    }

    // causal mask. D layout: row=(lane>>4)*4+r, col=lane&15 (m89-verified)
    const int rowg = q0 + wid * 16 + g4;
#pragma unroll
    for (int nt = 0; nt < 4; nt++) {
      int colg = kv0 + nt * 16 + l15;
#pragma unroll
      for (int r = 0; r < 4; r++)
        s[nt][r] = (colg > rowg + r) ? -1e30f : s[nt][r];
    }

    // online softmax, per row r (16 cols live in the 16 lanes of the subgroup)
    float pex[4][4];
    float corr[4];
#pragma unroll
    for (int r = 0; r < 4; r++) {
      float tm = fmaxf(fmaxf(s[0][r], s[1][r]), fmaxf(s[2][r], s[3][r]));
#pragma unroll
      for (int mask = 1; mask < 16; mask <<= 1) tm = fmaxf(tm, __shfl_xor(tm, mask));
      float mn = fmaxf(m_[r], tm);
      corr[r] = __expf(m_[r] - mn);
      m_[r] = mn;
      float rs = 0.f;
#pragma unroll
      for (int nt = 0; nt < 4; nt++) {
        float p = __expf(s[nt][r] - mn);
        pex[nt][r] = p;
        rs += p;
      }
#pragma unroll
      for (int mask = 1; mask < 16; mask <<= 1) rs += __shfl_xor(rs, mask);
      l_[r] = l_[r] * corr[r] + rs;
    }
#pragma unroll
    for (int dt = 0; dt < 8; dt++)
#pragma unroll
      for (int r = 0; r < 4; r++) acc[dt][r] *= corr[r];

    // P -> bf16 -> per-wave LDS (same-wave dep, no barrier needed)
#pragma unroll
    for (int nt = 0; nt < 4; nt++)
#pragma unroll
      for (int r = 0; r < 4; r++) Pl[wid][(g4 + r) * 68 + nt * 16 + l15] = f2bf(pex[nt][r]);

    // O += P @ V
#pragma unroll
    for (int k2 = 0; k2 < 2; k2++) {
      bf16x8 ap = ld_frag(&Pl[wid][l15 * 68 + k2 * 32 + g4]);
#pragma unroll
      for (int dt = 0; dt < 8; dt++) {
        bf16x8 bv = ld_frag(&Vt[(dt * 16 + l15) * 68 + k2 * 32 + g4]);
        acc[dt] = __builtin_amdgcn_mfma_f32_16x16x32_bf16(ap, bv, acc[dt], 0, 0, 0);
      }
    }
  }

  const long obase = ((long)(b * SEQ + q0 + wid * 16 + g4)) * (NH * HD) + (long)h * HD;
#pragma unroll
  for (int r = 0; r < 4; r++) {
    float inv = 1.f / l_[r];
#pragma unroll
    for (int dt = 0; dt < 8; dt++)
      attn_out[obase + (long)r * (NH * HD) + dt * 16 + l15] = f2bf(acc[dt][r] * inv);
  }
}

// ---------------- launch ----------------
extern "C" void kernel_launch(void* const* d_in, const int* in_sizes, int n_in,
                              void* d_out, int out_size, void* d_ws, size_t ws_size,
                              hipStream_t stream) {
  const float* x = (const float*)d_in[0];
  const float* Wq = (const float*)d_in[1];
  const float* Wk = (const float*)d_in[2];
  const float* Wv = (const float*)d_in[3];
  const float* Wo = (const float*)d_in[4];

  char* w = (char*)d_ws;
  float* ropetab = (float*)w;  w += (size_t)SEQ * HD * 4;
  short* xb  = (short*)w;  w += (size_t)MTOT * DIM * 2;
  short* WqT = (short*)w;  w += (size_t)DIM * DIM * 2;
  short* WkT = (short*)w;  w += (size_t)(KVH * HD) * DIM * 2;
  short* WvT = (short*)w;  w += (size_t)(KVH * HD) * DIM * 2;
  short* WoT = (short*)w;  w += (size_t)DIM * DIM * 2;
  short* q_r = (short*)w;  w += (size_t)BATCH * NH * SEQ * HD * 2;
  short* k_r = (short*)w;  w += (size_t)BATCH * KVH * SEQ * HD * 2;
  short* v_r = (short*)w;  w += (size_t)BATCH * KVH * SEQ * HD * 2;
  short* attn = (short*)w; w += (size_t)MTOT * DIM * 2;
  // v_t aliases xb: xb's last reader is k_gemm_kv, which precedes k_transpose_v in-stream.
  short* v_t = xb;

  k_rope_table<<<SEQ, 64, 0, stream>>>(ropetab);
  k_cvt_bf16<<<(MTOT * DIM / 4 + 255) / 256, 256, 0, stream>>>(x, xb, MTOT * DIM / 4);
  k_transpose<<<dim3(DIM / 32, DIM / 32), 256, 0, stream>>>(Wq, WqT, DIM, DIM);
  k_transpose<<<dim3((KVH * HD) / 32, DIM / 32), 256, 0, stream>>>(Wk, WkT, DIM, KVH * HD);
  k_transpose<<<dim3((KVH * HD) / 32, DIM / 32), 256, 0, stream>>>(Wv, WvT, DIM, KVH * HD);
  k_transpose<<<dim3(DIM / 32, DIM / 32), 256, 0, stream>>>(Wo, WoT, DIM, DIM);

  k_gemm_q<<<dim3(DIM / 128, MTOT / 128), 256, 0, stream>>>(xb, WqT, q_r, MTOT, DIM, DIM);
  k_gemm_kv<<<dim3((KVH * HD) / 128, MTOT / 128, 2), 256, 0, stream>>>(xb, WkT, WvT, k_r, v_r,
                                                                       MTOT, KVH * HD, DIM);
  k_transpose_v<<<dim3(SEQ / 64, HD / 64, BATCH * KVH), 256, 0, stream>>>(v_r, v_t);
  k_rope<<<(BATCH * NH * SEQ * 64 + 255) / 256, 256, 0, stream>>>(q_r, ropetab, BATCH * NH * SEQ * 64, SCALE);
  k_rope<<<(BATCH * KVH * SEQ * 64 + 255) / 256, 256, 0, stream>>>(k_r, ropetab, BATCH * KVH * SEQ * 64, 1.0f);

  k_attn<<<dim3(SEQ / 64, BATCH * NH), 256, 0, stream>>>(q_r, k_r, v_t, attn);
  k_gemm_o<<<dim3(DIM / 128, MTOT / 128), 256, 0, stream>>>(attn, WoT, (float*)d_out, MTOT, DIM, DIM);
}